// Round 1
// baseline (67.684 us; speedup 1.0000x reference)
//
#include <hip/hip_runtime.h>

#define MARGIN 0.1f
#define NBEST 64

// One wave (64 lanes) per batch row. 4 rows per 256-thread block.
__global__ __launch_bounds__(256)
void sml_kernel(const float* __restrict__ scores,
                const unsigned int* __restrict__ wr32,
                float* __restrict__ out, int B)
{
    const int lane = threadIdx.x & 63;
    const int rib  = threadIdx.x >> 6;          // row-in-block 0..3
    const int b    = blockIdx.x * 4 + rib;

    // Detect werRank element width (int64 vs int32).
    // If the array is int64 (little-endian, values in [0,64)), every odd
    // int32 word is 0. For genuine int32 ranks P(first 64 odd words all 0)
    // ~= (1/64)^64 ~ 0. Wave-uniform result.
    unsigned int probe = wr32[2 * lane + 1];
    const bool is64 = (__all(probe == 0u) != 0);

    __shared__ float g[4][NBEST];
    float gi = 0.0f;
    if (b < B) {
        int idx = b * NBEST + lane;
        unsigned int r = is64 ? wr32[2 * idx] : wr32[idx];
        gi = scores[b * NBEST + (int)(r & (NBEST - 1))];
        g[rib][lane] = gi;
    }
    __syncthreads();

    // acc = sum_{j>lane} max(g[j] - g[lane] + margin, 0)
    // Uniform 63-step loop; rotated LDS read (lane+k mod 64) is a
    // permutation across lanes -> 2 lanes/bank -> conflict-free.
    float acc = 0.0f;
    #pragma unroll
    for (int k = 1; k < NBEST; ++k) {
        int j = lane + k;
        float gj = g[rib][j & (NBEST - 1)];
        float h = gj - gi + MARGIN;
        acc += (j < NBEST) ? fmaxf(h, 0.0f) : 0.0f;
    }

    // REDUCTION='mean': divide by count of worse-ranked hyps (skip row N-1).
    int cnt = (NBEST - 1) - lane;
    if (cnt > 0) acc /= (float)cnt;

    // Wave-64 shuffle reduction.
    #pragma unroll
    for (int off = 32; off > 0; off >>= 1)
        acc += __shfl_down(acc, off);

    __shared__ float wsum[4];
    if (lane == 0) wsum[rib] = acc;
    __syncthreads();
    if (threadIdx.x == 0) {
        atomicAdd(out, wsum[0] + wsum[1] + wsum[2] + wsum[3]);
    }
}

extern "C" void kernel_launch(void* const* d_in, const int* in_sizes, int n_in,
                              void* d_out, int out_size, void* d_ws, size_t ws_size,
                              hipStream_t stream)
{
    const float* scores     = (const float*)d_in[0];
    const unsigned int* wr  = (const unsigned int*)d_in[1];
    const int B = in_sizes[0] / NBEST;

    // d_out is poisoned once before timing and never re-poisoned: zero it
    // ourselves every call (graph-capture-safe async memset).
    hipMemsetAsync(d_out, 0, (size_t)out_size * sizeof(float), stream);

    const int blocks = (B + 3) / 4;
    sml_kernel<<<blocks, 256, 0, stream>>>(scores, wr, (float*)d_out, B);
}

// Round 2
// 19.211 us; speedup vs baseline: 3.5231x; 3.5231x over previous
//
#include <hip/hip_runtime.h>

#define MARGIN 0.1f
#define NBEST 64

// One wave (64 lanes) per batch row. 4 rows per 256-thread block.
// Block partials go to d_ws (no same-address atomics); kernel 2 reduces.
__global__ __launch_bounds__(256)
void sml_kernel(const float* __restrict__ scores,
                const unsigned int* __restrict__ wr32,
                float* __restrict__ ws, int B)
{
    const int lane = threadIdx.x & 63;
    const int rib  = threadIdx.x >> 6;          // row-in-block 0..3
    const int b    = blockIdx.x * 4 + rib;

    // Detect werRank element width (int64 vs int32), wave-uniform.
    // int64 little-endian values in [0,64) -> every odd int32 word is 0.
    unsigned int probe = wr32[2 * lane + 1];
    const bool is64 = (__all(probe == 0u) != 0);

    __shared__ float4 gq4[4][NBEST / 4];
    float* g = (float*)gq4[rib];

    float gi = 0.0f;
    if (b < B) {
        int idx = b * NBEST + lane;
        unsigned int r = is64 ? wr32[2 * idx] : wr32[idx];
        gi = scores[b * NBEST + (int)(r & (NBEST - 1))];
        g[lane] = gi;
    }
    __syncthreads();

    // acc = sum_{j>lane} max(g[j] - gi + margin, 0)
    // Read the row as 16 float4 broadcasts (all lanes same addr ->
    // conflict-free). Predicate j>lane with cndmask; 2 accumulators.
    const float t = MARGIN - gi;
    float acc0 = 0.0f, acc1 = 0.0f;
    #pragma unroll
    for (int c = 0; c < NBEST / 4; ++c) {
        float4 q = gq4[rib][c];
        int j = 4 * c;
        float h0 = fmaxf(q.x + t, 0.0f); acc0 += (j + 0 > lane) ? h0 : 0.0f;
        float h1 = fmaxf(q.y + t, 0.0f); acc1 += (j + 1 > lane) ? h1 : 0.0f;
        float h2 = fmaxf(q.z + t, 0.0f); acc0 += (j + 2 > lane) ? h2 : 0.0f;
        float h3 = fmaxf(q.w + t, 0.0f); acc1 += (j + 3 > lane) ? h3 : 0.0f;
    }
    float acc = acc0 + acc1;

    // REDUCTION='mean': divide by count of worse-ranked hyps (row N-1 -> 0).
    int cnt = (NBEST - 1) - lane;
    if (cnt > 0) acc /= (float)cnt;
    if (b >= B) acc = 0.0f;

    // Wave-64 shuffle reduction.
    #pragma unroll
    for (int off = 32; off > 0; off >>= 1)
        acc += __shfl_down(acc, off);

    __shared__ float wsum[4];
    if (lane == 0) wsum[rib] = acc;
    __syncthreads();
    if (threadIdx.x == 0)
        ws[blockIdx.x] = wsum[0] + wsum[1] + wsum[2] + wsum[3];
}

// Single-block reduction of the per-block partials.
__global__ __launch_bounds__(256)
void sml_reduce(const float* __restrict__ ws, float* __restrict__ out, int n)
{
    const int lane = threadIdx.x & 63;
    const int wid  = threadIdx.x >> 6;

    float s = 0.0f;
    for (int i = threadIdx.x; i < n; i += 256) s += ws[i];

    #pragma unroll
    for (int off = 32; off > 0; off >>= 1)
        s += __shfl_down(s, off);

    __shared__ float wsum[4];
    if (lane == 0) wsum[wid] = s;
    __syncthreads();
    if (threadIdx.x == 0)
        out[0] = wsum[0] + wsum[1] + wsum[2] + wsum[3];
}

extern "C" void kernel_launch(void* const* d_in, const int* in_sizes, int n_in,
                              void* d_out, int out_size, void* d_ws, size_t ws_size,
                              hipStream_t stream)
{
    const float* scores     = (const float*)d_in[0];
    const unsigned int* wr  = (const unsigned int*)d_in[1];
    const int B = in_sizes[0] / NBEST;

    const int blocks = (B + 3) / 4;   // 4096 partials -> d_ws (16 KB)
    sml_kernel<<<blocks, 256, 0, stream>>>(scores, wr, (float*)d_ws, B);
    sml_reduce<<<1, 256, 0, stream>>>((const float*)d_ws, (float*)d_out, blocks);
}

// Round 3
// 13.783 us; speedup vs baseline: 4.9106x; 1.3938x over previous
//
#include <hip/hip_runtime.h>

#define MARGIN 0.1f
#define NBEST 64

// One wave processes 4 rows. Column-c values of the 4 rows are packed as a
// float4 in LDS: one ds_write_b128 per lane, one ds_read_b128 per column
// serves all 4 rows. Mask multiplier (c>lane) is shared across the 4 rows.
__global__ __launch_bounds__(256)
void sml_kernel(const float* __restrict__ scores,
                const unsigned int* __restrict__ wr32,
                float* __restrict__ ws, int B)
{
    const int lane = threadIdx.x & 63;
    const int wib  = threadIdx.x >> 6;            // wave-in-block 0..3
    const int wgl  = blockIdx.x * 4 + wib;        // global wave id
    const int b0   = wgl * 4;                     // first of this wave's 4 rows

    // werRank width probe (int64 vs int32), wave-uniform: int64 values in
    // [0,64) -> every odd int32 word is 0.
    unsigned int probe = wr32[2 * lane + 1];
    const bool is64 = (__all(probe == 0u) != 0);

    __shared__ float4 g4[4][NBEST];               // [wave][column] = 4 rows' g at column

    // Gather: this lane owns column i=lane of each of its 4 rows.
    float gv[4];
    #pragma unroll
    for (int r = 0; r < 4; ++r) {
        int b  = b0 + r;
        int bc = (b < B) ? b : (B - 1);           // clamp (never triggers for 16384)
        int idx = bc * NBEST + lane;
        unsigned int rk = is64 ? wr32[2 * idx] : wr32[idx];
        gv[r] = scores[bc * NBEST + (int)(rk & (NBEST - 1))];
    }
    float4 v = make_float4(gv[0], gv[1], gv[2], gv[3]);
    g4[wib][lane] = v;

    // t_r = margin - g_r[i], i = lane (own value, no LDS read needed)
    const float tx = MARGIN - v.x, ty = MARGIN - v.y;
    const float tz = MARGIN - v.z, tw = MARGIN - v.w;

    __syncthreads();

    // acc_r = sum_{c>lane} max(g_r[c] + t_r, 0)
    float a0 = 0.0f, a1 = 0.0f, a2 = 0.0f, a3 = 0.0f;
    #pragma unroll
    for (int c = 0; c < NBEST; ++c) {
        float4 q = g4[wib][c];
        float m01 = (c > lane) ? 1.0f : 0.0f;     // 1 cmp + 1 cndmask, shared x4
        a0 += fmaxf(q.x + tx, 0.0f) * m01;        // add, max, fmac per row
        a1 += fmaxf(q.y + ty, 0.0f) * m01;
        a2 += fmaxf(q.z + tz, 0.0f) * m01;
        a3 += fmaxf(q.w + tw, 0.0f) * m01;
    }

    // Zero contributions of rows beyond B (never for B=16384).
    if (b0 + 1 >= B) a1 = 0.0f;
    if (b0 + 2 >= B) a2 = 0.0f;
    if (b0 + 3 >= B) a3 = 0.0f;
    if (b0 >= B)     a0 = 0.0f;

    // mean over worse-ranked count; lane 63 has acc==0, just avoid div-by-0.
    int cnt = (NBEST - 1) - lane;
    float acc = (a0 + a1 + a2 + a3) / (float)(cnt > 0 ? cnt : 1);

    // Wave-64 shuffle reduction.
    #pragma unroll
    for (int off = 32; off > 0; off >>= 1)
        acc += __shfl_down(acc, off);

    __shared__ float wsum[4];
    if (lane == 0) wsum[wib] = acc;
    __syncthreads();
    if (threadIdx.x == 0)
        ws[blockIdx.x] = wsum[0] + wsum[1] + wsum[2] + wsum[3];
}

// Single-block reduction of per-block partials.
__global__ __launch_bounds__(256)
void sml_reduce(const float* __restrict__ ws, float* __restrict__ out, int n)
{
    const int lane = threadIdx.x & 63;
    const int wid  = threadIdx.x >> 6;

    float s = 0.0f;
    for (int i = threadIdx.x; i < n; i += 256) s += ws[i];

    #pragma unroll
    for (int off = 32; off > 0; off >>= 1)
        s += __shfl_down(s, off);

    __shared__ float wsum[4];
    if (lane == 0) wsum[wid] = s;
    __syncthreads();
    if (threadIdx.x == 0)
        out[0] = wsum[0] + wsum[1] + wsum[2] + wsum[3];
}

extern "C" void kernel_launch(void* const* d_in, const int* in_sizes, int n_in,
                              void* d_out, int out_size, void* d_ws, size_t ws_size,
                              hipStream_t stream)
{
    const float* scores     = (const float*)d_in[0];
    const unsigned int* wr  = (const unsigned int*)d_in[1];
    const int B = in_sizes[0] / NBEST;

    const int blocks = (B + 15) / 16;             // 1024 blocks, 16 rows each
    sml_kernel<<<blocks, 256, 0, stream>>>(scores, wr, (float*)d_ws, B);
    sml_reduce<<<1, 256, 0, stream>>>((const float*)d_ws, (float*)d_out, blocks);
}